// Round 11
// baseline (111.801 us; speedup 1.0000x reference)
//
#include <hip/hip_runtime.h>
#include <math.h>

// SP_loss: s = X X^T / T (N=8192, D=256, T=0.04, groups of 4).
// loss = mean_g softplus((neg[g] - margin[g]) / T)
//   neg[g]    = T * log sum_{i in g, j not in g} exp(s[i,j])
//               -> MX-fp8 (e4m3, K=128 scaled MFMA) symmetric GEMM over
//                  upper-tri 64x64 tiles, TPW=4 tiles/wave, 4 INDEPENDENT
//                  waves per 256-thread WG (no barrier/LDS/atomics/fences).
//   margin[g] = exact fp32 4x4 group Gram block (hard_pos / least_pos / alpha)
//
// R11 single-variable test: R10's gemm showed OccupancyPercent 7.2% (2.3
// waves/CU avg) against 8 waves/CU of available work -> suspected per-WG
// dispatch serialization (CP trickle-feeding 2064 one-wave WGs). This round
// packs 4 identical, fully-independent waves per WG (516 WGs, same per-wave
// instruction stream). If dispatch-limited, gemm collapses toward ~20 us;
// if unchanged, dispatch is exonerated.
//
// X quantized as fp8(x * 6.005612), 6.005612^2 = 25*log2(e): MFMA with unity
// E8M0 scales yields acc = s*log2(e) -> exp2f(acc) directly (verified
// R8-R10, absmax 0.0).

#define NROWS 8192
#define DDIM  256
#define NGRP  2048
#define NTB   128                       // 8192 / 64 tiles per dim
#define NTILES (NTB * (NTB + 1) / 2)    // 8256
#define TPW   4                         // tiles per wave
#define NWAVES (NTILES / TPW)           // 2064
#define WPB   4                         // independent waves per WG
#define NWG   (NWAVES / WPB)            // 516
#define T_CONST 0.04f
#define INV_T   25.0f
#define QSCALE  6.005612043932249f      // sqrt(25 * log2(e))
#define SCALE_ONE 0x7F7F7F7Fu           // E8M0 127 = 2^0 in every byte

typedef __attribute__((ext_vector_type(8))) int   i32x8_t;
typedef __attribute__((ext_vector_type(4))) int   i32x4_t;
typedef __attribute__((ext_vector_type(4))) float f32x4_t;

__device__ __forceinline__ i32x8_t ldfrag(const unsigned char* base, int off) {
    i32x4_t lo = *(const i32x4_t*)(base + off);
    i32x4_t hi = *(const i32x4_t*)(base + off + 16);
    return __builtin_shufflevector(lo, hi, 0, 1, 2, 3, 4, 5, 6, 7);
}

// Kernel A (fused prep): blocks 0..511 convert fp32 -> fp8 e4m3 (x*QSCALE, RNE,
// x4 per thread) + zero out[0]; blocks 512..1023 compute margin[g]
// (4 groups/block, 1 wave each).
__global__ __launch_bounds__(256) void prep_kernel(const float* __restrict__ x,
                                                   unsigned int* __restrict__ xq,
                                                   float* __restrict__ margin,
                                                   float* __restrict__ out) {
    const int b = blockIdx.x;
    if (b < 512) {
        if (b == 0 && threadIdx.x == 0) out[0] = 0.f;   // finalize atomicAdds into it
#pragma unroll
        for (int it = 0; it < 4; ++it) {
            int gid = it * 131072 + b * 256 + threadIdx.x;
            float4 v = *(const float4*)(x + (size_t)gid * 4);
            int pk = __builtin_amdgcn_cvt_pk_fp8_f32(v.x * QSCALE, v.y * QSCALE, 0, false);
            pk = __builtin_amdgcn_cvt_pk_fp8_f32(v.z * QSCALE, v.w * QSCALE, pk, true);
            xq[gid] = (unsigned int)pk;
        }
        return;
    }
    const int g = (b - 512) * 4 + (threadIdx.x >> 6);
    const int lane = threadIdx.x & 63;
    const float* xr = x + (size_t)g * 4 * DDIM;
    float a[16];
#pragma unroll
    for (int k = 0; k < 16; ++k) a[k] = 0.f;
    for (int e = lane; e < DDIM; e += 64) {
        float vv[4];
        vv[0] = xr[e];
        vv[1] = xr[DDIM + e];
        vv[2] = xr[2 * DDIM + e];
        vv[3] = xr[3 * DDIM + e];
#pragma unroll
        for (int i = 0; i < 4; ++i)
#pragma unroll
            for (int j = 0; j < 4; ++j)
                a[i * 4 + j] = fmaf(vv[i], vv[j], a[i * 4 + j]);
    }
#pragma unroll
    for (int k = 0; k < 16; ++k) {
        float t = a[k];
        t += __shfl_xor(t, 32, 64);
        t += __shfl_xor(t, 16, 64);
        t += __shfl_xor(t, 8, 64);
        t += __shfl_xor(t, 4, 64);
        t += __shfl_xor(t, 2, 64);
        t += __shfl_xor(t, 1, 64);
        a[k] = t;
    }
    if (lane == 0) {
        float pos[16];
#pragma unroll
        for (int k = 0; k < 16; ++k) pos[k] = a[k] * INV_T;

        float mx = -pos[0];
#pragma unroll
        for (int k = 1; k < 16; ++k) mx = fmaxf(mx, -pos[k]);
        float se = 0.f;
#pragma unroll
        for (int k = 0; k < 16; ++k) se += __expf(-pos[k] - mx);
        float hard_pos = -T_CONST * (mx + __logf(se));

        float lse_row[4];
#pragma unroll
        for (int i = 0; i < 4; ++i) {
            float m2 = -pos[i * 4];
#pragma unroll
            for (int j = 1; j < 4; ++j) m2 = fmaxf(m2, -pos[i * 4 + j]);
            float s2 = 0.f;
#pragma unroll
            for (int j = 0; j < 4; ++j) s2 += __expf(-pos[i * 4 + j] - m2);
            lse_row[i] = m2 + __logf(s2);
        }
        float m3 = -lse_row[0];
#pragma unroll
        for (int i = 1; i < 4; ++i) m3 = fmaxf(m3, -lse_row[i]);
        float s3 = 0.f;
#pragma unroll
        for (int i = 0; i < 4; ++i) s3 += __expf(-lse_row[i] - m3);
        float least_pos = T_CONST * (m3 + __logf(s3));

        float alpha = (hard_pos >= 0.f)
                          ? (2.f * least_pos * hard_pos) / (hard_pos + least_pos)
                          : 0.f;
        margin[g] = alpha * hard_pos + (1.f - alpha) * least_pos;
    }
}

// Kernel B: 256-thread WGs, 4 fully-independent waves; wave w of block b
// executes exactly R10's wave (blockIdx*4+w): TPW=4 consecutive upper-tri
// 64x64 tiles. acc C/D layout (verified R4-R10): col = ni*16 + l16,
// row = mi*16 + quad*4 + reg -> reg spans exactly one group of 4 rows.
// contrib[p][q][idx] written exactly once across the grid (run-combined row
// sums + explicit zeros on p<=q; col sums on p>q).
__global__ __launch_bounds__(256) void gemm_exp_contrib(const unsigned char* __restrict__ xq,
                                                        float* __restrict__ contrib) {
    const int waveId = threadIdx.x >> 6;
    const int idx0 = (blockIdx.x * WPB + waveId) * TPW;
    int ti = (int)((257.0f - sqrtf(66049.0f - 8.0f * (float)idx0)) * 0.5f);
    while (ti * (257 - ti) / 2 > idx0) --ti;
    while ((ti + 1) * (256 - ti) / 2 <= idx0) ++ti;
    int tj = ti + (idx0 - ti * (257 - ti) / 2);

    const int lane = threadIdx.x & 63;
    const int quad = lane >> 4;
    const int l16 = lane & 15;

    // per-lane fragment byte offsets: voff[ks*4+i] = ((i*16+l16)<<8) + ks*128 + quad*32
    int voff[8];
#pragma unroll
    for (int z = 0; z < 8; ++z)
        voff[z] = (((z & 3) * 16 + l16) << 8) + (z >> 2) * 128 + quad * 32;

    i32x8_t aF[2][4];            // A fragments, full K, persist across the run
    int curTi = -1;

    int runTi = ti, runTj = tj;  // first tile of the current same-ti run
    bool isStart = true;
    float rowgAcc[4] = {0.f, 0.f, 0.f, 0.f};

    for (int t = 0; t < TPW; ++t) {
        const bool diag = (ti == tj);

        if (ti != curTi) {       // wave-uniform; ~once per wave
            curTi = ti;
            const unsigned char* ab = xq + ((size_t)ti << 14);
#pragma unroll
            for (int z = 0; z < 8; ++z) aF[z >> 2][z & 3] = ldfrag(ab, voff[z]);
        }

        // batch ALL 16 B-fragment loads, single implicit vmcnt wait at first MFMA
        i32x8_t bF[2][4];
        {
            const unsigned char* bb = xq + ((size_t)tj << 14);
#pragma unroll
            for (int z = 0; z < 8; ++z) bF[z >> 2][z & 3] = ldfrag(bb, voff[z]);
        }

        f32x4_t acc[4][4];
#pragma unroll
        for (int i = 0; i < 4; ++i)
#pragma unroll
            for (int j = 0; j < 4; ++j)
                acc[i][j] = (f32x4_t){0.f, 0.f, 0.f, 0.f};

#pragma unroll
        for (int ks = 0; ks < 2; ++ks)
#pragma unroll
            for (int mi = 0; mi < 4; ++mi)
#pragma unroll
                for (int ni = 0; ni < 4; ++ni)
                    acc[mi][ni] = __builtin_amdgcn_mfma_scale_f32_16x16x128_f8f6f4(
                        aF[ks][mi], bF[ks][ni], acc[mi][ni],
                        0, 0,                       // fp8 e4m3 A and B
                        0, (int)SCALE_ONE,          // scale A = 1
                        0, (int)SCALE_ONE);         // scale B = 1

        // ---- epilogue: acc = s*log2(e); exp2 + group partials ----
        float colp[4] = {0.f, 0.f, 0.f, 0.f};
        if (!diag) {
#pragma unroll
            for (int mi = 0; mi < 4; ++mi)
#pragma unroll
                for (int ni = 0; ni < 4; ++ni) {
                    float s4 = exp2f(acc[mi][ni][0]) + exp2f(acc[mi][ni][1])
                             + exp2f(acc[mi][ni][2]) + exp2f(acc[mi][ni][3]);
                    rowgAcc[mi] += s4;
                    colp[ni] += s4;
                }
        } else {
#pragma unroll
            for (int mi = 0; mi < 4; ++mi) {
                const int rgrp = mi * 4 + quad;
#pragma unroll
                for (int ni = 0; ni < 4; ++ni) {
                    const int cgrp = ni * 4 + (l16 >> 2);
                    if (cgrp != rgrp) {
                        float s4 = exp2f(acc[mi][ni][0]) + exp2f(acc[mi][ni][1])
                                 + exp2f(acc[mi][ni][2]) + exp2f(acc[mi][ni][3]);
                        rowgAcc[mi] += s4;   // rows only on diag
                    }
                }
            }
        }

        // non-run-start tiles: their row slot gets zeros (combined sum lands
        // in the run-start slot at flush)
        if (!isStart && l16 == 0) {
            float* crow = contrib + (((size_t)ti * NTB + tj) << 4);
#pragma unroll
            for (int mi = 0; mi < 4; ++mi) crow[mi * 4 + quad] = 0.f;
        }

        if (!diag) {
            // col groups -> contrib[tj][ti][ni*4+(l16>>2)] (per tile)
            float* ccol = contrib + (((size_t)tj * NTB + ti) << 4);
#pragma unroll
            for (int ni = 0; ni < 4; ++ni) {
                float v = colp[ni];
                v += __shfl_xor(v, 16, 64);
                v += __shfl_xor(v, 32, 64);
                v += __shfl_xor(v, 1, 64);
                v += __shfl_xor(v, 2, 64);
                if (quad == 0 && (l16 & 3) == 0) ccol[ni * 4 + (l16 >> 2)] = v;
            }
        }

        // advance; flush the run's combined row sums when ti changes or wave ends
        int nti = ti, ntj = tj + 1;
        if (ntj == NTB) { ++nti; ntj = nti; }
        const bool flush = (t == TPW - 1) || (nti != runTi);
        if (flush) {
            float* crow = contrib + (((size_t)runTi * NTB + runTj) << 4);
#pragma unroll
            for (int mi = 0; mi < 4; ++mi) {
                float v = rowgAcc[mi];
                v += __shfl_xor(v, 1, 64);
                v += __shfl_xor(v, 2, 64);
                v += __shfl_xor(v, 4, 64);
                v += __shfl_xor(v, 8, 64);
                if (l16 == 0) crow[mi * 4 + quad] = v;
                rowgAcc[mi] = 0.f;
            }
            runTi = nti; runTj = ntj;
            isStart = true;
        } else {
            isStart = false;
        }
        ti = nti; tj = ntj;
    }
}

// Kernel C: 8 WGs x 256 threads, one thread per group g.
// neg[g] = T*log(sum_q contrib[g>>4][q][g&15]); block-reduced softplus sums
// atomicAdd into out[0] (zeroed by prep). 8 atomics total.
__global__ __launch_bounds__(256) void finalize_kernel(const float* __restrict__ contrib,
                                                       const float* __restrict__ margin,
                                                       float* __restrict__ out) {
    const int tid = threadIdx.x;
    const int g = blockIdx.x * 256 + tid;
    const int p = g >> 4;
    const int idx = g & 15;
    const float* base = contrib + (((size_t)p * NTB) << 4) + idx;
    float s = 0.f;
#pragma unroll 4
    for (int q = 0; q < NTB; ++q) s += base[(size_t)q << 4];
    float z = __logf(s) - margin[g] * INV_T;   // (neg - margin)/T
    float local = (z > 30.f) ? z : log1pf(__expf(z));

    local += __shfl_xor(local, 1, 64);
    local += __shfl_xor(local, 2, 64);
    local += __shfl_xor(local, 4, 64);
    local += __shfl_xor(local, 8, 64);
    local += __shfl_xor(local, 16, 64);
    local += __shfl_xor(local, 32, 64);
    __shared__ float wsum[4];
    if ((tid & 63) == 0) wsum[tid >> 6] = local;
    __syncthreads();
    if (tid == 0)
        atomicAdd(out, (wsum[0] + wsum[1] + wsum[2] + wsum[3]) * (1.f / (float)NGRP));
}

extern "C" void kernel_launch(void* const* d_in, const int* in_sizes, int n_in,
                              void* d_out, int out_size, void* d_ws, size_t ws_size,
                              hipStream_t stream) {
    const float* x = (const float*)d_in[0];
    float* out = (float*)d_out;

    unsigned int* xq = (unsigned int*)d_ws;                                  // 2 MiB fp8 X*c
    float* contrib = (float*)((char*)d_ws + (size_t)NROWS * DDIM);           // 1 MiB partials
    float* margin = contrib + (size_t)NTB * NTB * 16;                        // 8 KiB

    prep_kernel<<<1024, 256, 0, stream>>>(x, xq, margin, out);
    gemm_exp_contrib<<<NWG, 256, 0, stream>>>((const unsigned char*)xq, contrib);
    finalize_kernel<<<8, 256, 0, stream>>>(contrib, margin, out);
}

// Round 12
// 105.155 us; speedup vs baseline: 1.0632x; 1.0632x over previous
//
#include <hip/hip_runtime.h>
#include <math.h>

// SP_loss: s = X X^T / T (N=8192, D=256, T=0.04, groups of 4).
// loss = mean_g softplus((neg[g] - margin[g]) / T)
//   neg[g]    = T * log sum_{i in g, j not in g} exp(s[i,j])
//               -> MX-fp8 (e4m3, K=128 scaled MFMA) symmetric GEMM over
//                  upper-tri 64x64 tiles, TPW=2 tiles/wave, 4 independent
//                  waves per WG, no LDS/barriers/atomics/fences in hot loop.
//   margin[g] = exact fp32 4x4 group Gram block (hard_pos / least_pos / alpha)
//
// R12 (instruction diet, after R6-R11 falsified all structural theories):
//  - exp2f was lowering to libm's ~8-10-instr denormal-guarded sequence (the
//    anomalous VALUBusy). Now QSCALE=5 (5^2 = 25 = 1/T) -> acc = s exactly,
//    epilogue uses __expf (native v_mul+v_exp_f32, 2 instr).
//  - fragment loads: single contiguous i32x8 load (2 adjacent dwordx4, no
//    shufflevector movs, half the address processing).
//  - TPW=2 -> 4128 waves (4 waves/SIMD of work) for latency hiding.
//  - prep margin dots via float4 loads (4 loads/row-pair instead of 16).

#define NROWS 8192
#define DDIM  256
#define NGRP  2048
#define NTB   128                       // 8192 / 64 tiles per dim
#define NTILES (NTB * (NTB + 1) / 2)    // 8256
#define TPW   2                         // tiles per wave
#define NWAVES (NTILES / TPW)           // 4128
#define WPB   4                         // independent waves per WG
#define NWG   (NWAVES / WPB)            // 1032
#define T_CONST 0.04f
#define INV_T   25.0f
#define QSCALE  5.0f                    // sqrt(1/T): acc = s exactly
#define SCALE_ONE 0x7F7F7F7Fu           // E8M0 127 = 2^0 in every byte

typedef __attribute__((ext_vector_type(8))) int   i32x8_t;
typedef __attribute__((ext_vector_type(4))) float f32x4_t;

// Kernel A (fused prep): blocks 0..511 convert fp32 -> fp8 e4m3 (x*QSCALE, RNE,
// x4 per thread) + zero out[0]; blocks 512..1023 compute margin[g]
// (4 groups/block, 1 wave each, float4 loads).
__global__ __launch_bounds__(256) void prep_kernel(const float* __restrict__ x,
                                                   unsigned int* __restrict__ xq,
                                                   float* __restrict__ margin,
                                                   float* __restrict__ out) {
    const int b = blockIdx.x;
    if (b < 512) {
        if (b == 0 && threadIdx.x == 0) out[0] = 0.f;   // finalize atomicAdds into it
#pragma unroll
        for (int it = 0; it < 4; ++it) {
            int gid = it * 131072 + b * 256 + threadIdx.x;
            float4 v = *(const float4*)(x + (size_t)gid * 4);
            int pk = __builtin_amdgcn_cvt_pk_fp8_f32(v.x * QSCALE, v.y * QSCALE, 0, false);
            pk = __builtin_amdgcn_cvt_pk_fp8_f32(v.z * QSCALE, v.w * QSCALE, pk, true);
            xq[gid] = (unsigned int)pk;
        }
        return;
    }
    const int g = (b - 512) * 4 + (threadIdx.x >> 6);
    const int lane = threadIdx.x & 63;
    const float* xr = x + (size_t)g * 4 * DDIM;
    // lane covers elements [4*lane, 4*lane+4) of each of the 4 rows
    float4 v0 = *(const float4*)(xr + 4 * lane);
    float4 v1 = *(const float4*)(xr + DDIM + 4 * lane);
    float4 v2 = *(const float4*)(xr + 2 * DDIM + 4 * lane);
    float4 v3 = *(const float4*)(xr + 3 * DDIM + 4 * lane);
    float4 vv[4] = {v0, v1, v2, v3};
    float a[16];
#pragma unroll
    for (int i = 0; i < 4; ++i)
#pragma unroll
        for (int j = 0; j < 4; ++j) {
            float d = vv[i].x * vv[j].x + vv[i].y * vv[j].y
                    + vv[i].z * vv[j].z + vv[i].w * vv[j].w;
            a[i * 4 + j] = d;
        }
#pragma unroll
    for (int k = 0; k < 16; ++k) {
        float t = a[k];
        t += __shfl_xor(t, 32, 64);
        t += __shfl_xor(t, 16, 64);
        t += __shfl_xor(t, 8, 64);
        t += __shfl_xor(t, 4, 64);
        t += __shfl_xor(t, 2, 64);
        t += __shfl_xor(t, 1, 64);
        a[k] = t;
    }
    if (lane == 0) {
        float pos[16];
#pragma unroll
        for (int k = 0; k < 16; ++k) pos[k] = a[k] * INV_T;

        float mx = -pos[0];
#pragma unroll
        for (int k = 1; k < 16; ++k) mx = fmaxf(mx, -pos[k]);
        float se = 0.f;
#pragma unroll
        for (int k = 0; k < 16; ++k) se += __expf(-pos[k] - mx);
        float hard_pos = -T_CONST * (mx + __logf(se));

        float lse_row[4];
#pragma unroll
        for (int i = 0; i < 4; ++i) {
            float m2 = -pos[i * 4];
#pragma unroll
            for (int j = 1; j < 4; ++j) m2 = fmaxf(m2, -pos[i * 4 + j]);
            float s2 = 0.f;
#pragma unroll
            for (int j = 0; j < 4; ++j) s2 += __expf(-pos[i * 4 + j] - m2);
            lse_row[i] = m2 + __logf(s2);
        }
        float m3 = -lse_row[0];
#pragma unroll
        for (int i = 1; i < 4; ++i) m3 = fmaxf(m3, -lse_row[i]);
        float s3 = 0.f;
#pragma unroll
        for (int i = 0; i < 4; ++i) s3 += __expf(-lse_row[i] - m3);
        float least_pos = T_CONST * (m3 + __logf(s3));

        float alpha = (hard_pos >= 0.f)
                          ? (2.f * least_pos * hard_pos) / (hard_pos + least_pos)
                          : 0.f;
        margin[g] = alpha * hard_pos + (1.f - alpha) * least_pos;
    }
}

// Kernel B: 256-thread WGs, 4 independent waves; wave handles TPW=2
// consecutive upper-tri 64x64 tiles. acc C/D layout (verified R4-R11):
// col = ni*16 + l16, row = mi*16 + quad*4 + reg -> reg spans one group.
// contrib[p][q][idx] written exactly once (run-combined rows + zeros on
// p<=q; col sums on p>q).
__global__ __launch_bounds__(256) void gemm_exp_contrib(const unsigned char* __restrict__ xq,
                                                        float* __restrict__ contrib) {
    const int waveId = threadIdx.x >> 6;
    const int idx0 = (blockIdx.x * WPB + waveId) * TPW;
    int ti = (int)((257.0f - sqrtf(66049.0f - 8.0f * (float)idx0)) * 0.5f);
    while (ti * (257 - ti) / 2 > idx0) --ti;
    while ((ti + 1) * (256 - ti) / 2 <= idx0) ++ti;
    int tj = ti + (idx0 - ti * (257 - ti) / 2);

    const int lane = threadIdx.x & 63;
    const int quad = lane >> 4;
    const int l16 = lane & 15;

    // per-lane fragment byte offsets (contiguous 32 B each):
    // voff[ks*4+i] = ((i*16+l16)<<8) + ks*128 + quad*32
    int voff[8];
#pragma unroll
    for (int z = 0; z < 8; ++z)
        voff[z] = (((z & 3) * 16 + l16) << 8) + (z >> 2) * 128 + quad * 32;

    i32x8_t aF[2][4];            // A fragments, full K, persist across the run
    int curTi = -1;

    int runTi = ti, runTj = tj;  // first tile of the current same-ti run
    bool isStart = true;
    float rowgAcc[4] = {0.f, 0.f, 0.f, 0.f};

    for (int t = 0; t < TPW; ++t) {
        const bool diag = (ti == tj);

        if (ti != curTi) {       // wave-uniform
            curTi = ti;
            const unsigned char* ab = xq + ((size_t)ti << 14);
#pragma unroll
            for (int z = 0; z < 8; ++z)
                aF[z >> 2][z & 3] = *(const i32x8_t*)(ab + voff[z]);
        }

        // all 16 B-fragment loads (8 x 32-B contiguous), one vmcnt wait at MFMA
        i32x8_t bF[2][4];
        {
            const unsigned char* bb = xq + ((size_t)tj << 14);
#pragma unroll
            for (int z = 0; z < 8; ++z)
                bF[z >> 2][z & 3] = *(const i32x8_t*)(bb + voff[z]);
        }

        f32x4_t acc[4][4];
#pragma unroll
        for (int i = 0; i < 4; ++i)
#pragma unroll
            for (int j = 0; j < 4; ++j)
                acc[i][j] = (f32x4_t){0.f, 0.f, 0.f, 0.f};

#pragma unroll
        for (int ks = 0; ks < 2; ++ks)
#pragma unroll
            for (int mi = 0; mi < 4; ++mi)
#pragma unroll
                for (int ni = 0; ni < 4; ++ni)
                    acc[mi][ni] = __builtin_amdgcn_mfma_scale_f32_16x16x128_f8f6f4(
                        aF[ks][mi], bF[ks][ni], acc[mi][ni],
                        0, 0,                       // fp8 e4m3 A and B
                        0, (int)SCALE_ONE,          // scale A = 1
                        0, (int)SCALE_ONE);         // scale B = 1

        // ---- epilogue: acc = s; native exp (__expf) + group partials ----
        float colp[4] = {0.f, 0.f, 0.f, 0.f};
        if (!diag) {
#pragma unroll
            for (int mi = 0; mi < 4; ++mi)
#pragma unroll
                for (int ni = 0; ni < 4; ++ni) {
                    float s4 = __expf(acc[mi][ni][0]) + __expf(acc[mi][ni][1])
                             + __expf(acc[mi][ni][2]) + __expf(acc[mi][ni][3]);
                    rowgAcc[mi] += s4;
                    colp[ni] += s4;
                }
        } else {
#pragma unroll
            for (int mi = 0; mi < 4; ++mi) {
                const int rgrp = mi * 4 + quad;
#pragma unroll
                for (int ni = 0; ni < 4; ++ni) {
                    const int cgrp = ni * 4 + (l16 >> 2);
                    if (cgrp != rgrp) {
                        float s4 = __expf(acc[mi][ni][0]) + __expf(acc[mi][ni][1])
                                 + __expf(acc[mi][ni][2]) + __expf(acc[mi][ni][3]);
                        rowgAcc[mi] += s4;   // rows only on diag
                    }
                }
            }
        }

        // non-run-start tiles: row slot gets zeros (combined sum lands at flush)
        if (!isStart && l16 == 0) {
            float* crow = contrib + (((size_t)ti * NTB + tj) << 4);
#pragma unroll
            for (int mi = 0; mi < 4; ++mi) crow[mi * 4 + quad] = 0.f;
        }

        if (!diag) {
            // col groups -> contrib[tj][ti][ni*4+(l16>>2)]
            float* ccol = contrib + (((size_t)tj * NTB + ti) << 4);
#pragma unroll
            for (int ni = 0; ni < 4; ++ni) {
                float v = colp[ni];
                v += __shfl_xor(v, 16, 64);
                v += __shfl_xor(v, 32, 64);
                v += __shfl_xor(v, 1, 64);
                v += __shfl_xor(v, 2, 64);
                if (quad == 0 && (l16 & 3) == 0) ccol[ni * 4 + (l16 >> 2)] = v;
            }
        }

        // advance; flush run's combined row sums when ti changes or wave ends
        int nti = ti, ntj = tj + 1;
        if (ntj == NTB) { ++nti; ntj = nti; }
        const bool flush = (t == TPW - 1) || (nti != runTi);
        if (flush) {
            float* crow = contrib + (((size_t)runTi * NTB + runTj) << 4);
#pragma unroll
            for (int mi = 0; mi < 4; ++mi) {
                float v = rowgAcc[mi];
                v += __shfl_xor(v, 1, 64);
                v += __shfl_xor(v, 2, 64);
                v += __shfl_xor(v, 4, 64);
                v += __shfl_xor(v, 8, 64);
                if (l16 == 0) crow[mi * 4 + quad] = v;
                rowgAcc[mi] = 0.f;
            }
            runTi = nti; runTj = ntj;
            isStart = true;
        } else {
            isStart = false;
        }
        ti = nti; tj = ntj;
    }
}

// Kernel C: 8 WGs x 256 threads, one thread per group g.
// neg[g] = T*log(sum_q contrib[g>>4][q][g&15]); block-reduced softplus sums
// atomicAdd into out[0] (zeroed by prep). 8 atomics total.
__global__ __launch_bounds__(256) void finalize_kernel(const float* __restrict__ contrib,
                                                       const float* __restrict__ margin,
                                                       float* __restrict__ out) {
    const int tid = threadIdx.x;
    const int g = blockIdx.x * 256 + tid;
    const int p = g >> 4;
    const int idx = g & 15;
    const float* base = contrib + (((size_t)p * NTB) << 4) + idx;
    float s = 0.f;
#pragma unroll 4
    for (int q = 0; q < NTB; ++q) s += base[(size_t)q << 4];
    float z = __logf(s) - margin[g] * INV_T;   // (neg - margin)/T
    float local = (z > 30.f) ? z : log1pf(__expf(z));

    local += __shfl_xor(local, 1, 64);
    local += __shfl_xor(local, 2, 64);
    local += __shfl_xor(local, 4, 64);
    local += __shfl_xor(local, 8, 64);
    local += __shfl_xor(local, 16, 64);
    local += __shfl_xor(local, 32, 64);
    __shared__ float wsum[4];
    if ((tid & 63) == 0) wsum[tid >> 6] = local;
    __syncthreads();
    if (tid == 0)
        atomicAdd(out, (wsum[0] + wsum[1] + wsum[2] + wsum[3]) * (1.f / (float)NGRP));
}

extern "C" void kernel_launch(void* const* d_in, const int* in_sizes, int n_in,
                              void* d_out, int out_size, void* d_ws, size_t ws_size,
                              hipStream_t stream) {
    const float* x = (const float*)d_in[0];
    float* out = (float*)d_out;

    unsigned int* xq = (unsigned int*)d_ws;                                  // 2 MiB fp8 X*5
    float* contrib = (float*)((char*)d_ws + (size_t)NROWS * DDIM);           // 1 MiB partials
    float* margin = contrib + (size_t)NTB * NTB * 16;                        // 8 KiB

    prep_kernel<<<1024, 256, 0, stream>>>(x, xq, margin, out);
    gemm_exp_contrib<<<NWG, 256, 0, stream>>>((const unsigned char*)xq, contrib);
    finalize_kernel<<<8, 256, 0, stream>>>(contrib, margin, out);
}